// Round 3
// baseline (115.233 us; speedup 1.0000x reference)
//
#include <hip/hip_runtime.h>
#include <hip/hip_bf16.h>

namespace {

constexpr int Bc = 2, Hc = 16, Lc = 2048, Dc = 128;
constexpr int KVBLK = 64;
constexpr int BH  = Bc * Hc;      // 32
constexpr int NKT = Lc / KVBLK;   // 32
constexpr int QB3 = 128;          // q rows per block (R3)
constexpr int NQT3 = Lc / QB3;    // 16
// 1/sqrt(128) * log2(e)  (softmax in exp2 domain)
constexpr float SCALE = 0.08838834764831845f * 1.4426950408889634f;

using f32x4  = __attribute__((ext_vector_type(4))) float;
using short8 = __attribute__((ext_vector_type(8))) short;

union FragU { short8 v; short4 h[2]; };

__device__ inline short f2bf(float f) {
  unsigned u = __builtin_bit_cast(unsigned, f);
  u += 0x7fffu + ((u >> 16) & 1u);          // RNE
  return (short)(u >> 16);
}

__device__ inline void gload_lds16(const short* g, short* l) {
  __builtin_amdgcn_global_load_lds(
      (const __attribute__((address_space(1))) void*)g,
      (__attribute__((address_space(3))) void*)l, 16, 0, 0);
}

// ===================== pre-pass: K fp32 -> bf16, swizzled tiles =====================
// Kw layout: per (bh*32+t) tile of 16 KB: byte addr row*256 + ((col*2) ^ ((row&7)<<4))
__global__ __launch_bounds__(256) void conv_k(const float* __restrict__ Kg,
                                              short* __restrict__ Kw) {
  int tid = blockIdx.x * 256 + threadIdx.x;   // 1,048,576 total
  int x   = tid & 15;                         // dest 16B granule in row
  int row = (tid >> 4) & 63;
  int tb  = tid >> 10;                        // bh*32 + t
  int xs  = x ^ (row & 7);                    // source granule
  const float* src = Kg + ((size_t)tb * 64 + row) * 128 + xs * 8;
  float4 a = *(const float4*)src;
  float4 b = *(const float4*)(src + 4);
  short8 v;
  v[0] = f2bf(a.x); v[1] = f2bf(a.y); v[2] = f2bf(a.z); v[3] = f2bf(a.w);
  v[4] = f2bf(b.x); v[5] = f2bf(b.y); v[6] = f2bf(b.z); v[7] = f2bf(b.w);
  *(short8*)(Kw + (size_t)tb * 8192 + row * 128 + x * 8) = v;
}

// ===================== pre-pass: V fp32 -> bf16 transposed, swizzled =====================
// Vw layout: per tile 16 KB: byte addr d*128 + ((kv*2) ^ ((d&7)<<4))
__global__ __launch_bounds__(256) void conv_v(const float* __restrict__ Vg,
                                              short* __restrict__ Vw) {
  __shared__ short Vs[64 * 130];
  int tb  = blockIdx.x;                       // bh*32 + t
  int tid = threadIdx.x;
  const float* vt = Vg + (size_t)tb * 8192;
#pragma unroll
  for (int p = 0; p < 8; ++p) {
    int g  = p * 256 + tid;                   // float4 index 0..2047
    int kv = g >> 5;
    int c4 = g & 31;
    float4 v = *((const float4*)vt + g);
    short* d = &Vs[kv * 130 + c4 * 4];
    d[0] = f2bf(v.x); d[1] = f2bf(v.y); d[2] = f2bf(v.z); d[3] = f2bf(v.w);
  }
  __syncthreads();
#pragma unroll
  for (int p = 0; p < 4; ++p) {
    int g = p * 256 + tid;                    // dest granule 0..1023
    int d = g >> 3;
    int x = g & 7;
    int kv0 = (x ^ (d & 7)) * 8;
    short8 o;
#pragma unroll
    for (int j = 0; j < 8; ++j) o[j] = Vs[(kv0 + j) * 130 + d];
    *(short8*)(Vw + (size_t)tb * 8192 + d * 64 + x * 8) = o;
  }
}

// ===================== main attention (R3: 8 waves, QBLK=128) =====================
__global__ __launch_bounds__(512, 4) void attn_fwd3(
    const float* __restrict__ Qg, const short* __restrict__ Kw,
    const short* __restrict__ Vw, float* __restrict__ Og) {

  // [buf][K=0 / V=1][8192 shorts] = 64 KB -> 2 blocks/CU
  __shared__ __align__(16) short lds[2][2][8192];

  const int tid  = threadIdx.x;
  const int wave = tid >> 6;
  const int lane = tid & 63;
  const int lg   = lane >> 4;
  const int lr   = lane & 15;
  const int sw   = (lr & 7) << 4;             // XOR swizzle (row&7 == lr&7 in all reads)

  const int bid = blockIdx.x;
  const int bh  = bid & (BH - 1);             // bid%8 == bh%8 -> head-per-XCD L2 locality
  const int r5  = bid >> 5;                   // 0..15
  // anti-correlated qt: CU's two resident blocks (bid, bid+256) sum to 34 tiles
  const int qt  = (bid < 256) ? (NQT3 - 1 - r5) : (r5 - 8);
  const int q0w = qt * QB3 + wave * 16;

  const float* Qp = Qg + (size_t)bh * Lc * Dc;
  float*       Op = Og + (size_t)bh * Lc * Dc;
  const short* Kwp = Kw + (size_t)bh * NKT * 8192;
  const short* Vwp = Vw + (size_t)bh * NKT * 8192;

  // ---- preload Q fragments (B-operand layout), pre-scaled ----
  short8 qf[4];
  {
    const float* qrow = Qp + (size_t)(q0w + lr) * Dc;
#pragma unroll
    for (int dc = 0; dc < 4; ++dc) {
      float4 a = *(const float4*)(qrow + dc * 32 + lg * 4);
      float4 b = *(const float4*)(qrow + dc * 32 + 16 + lg * 4);
      short8 v;
      v[0] = f2bf(a.x * SCALE); v[1] = f2bf(a.y * SCALE);
      v[2] = f2bf(a.z * SCALE); v[3] = f2bf(a.w * SCALE);
      v[4] = f2bf(b.x * SCALE); v[5] = f2bf(b.y * SCALE);
      v[6] = f2bf(b.z * SCALE); v[7] = f2bf(b.w * SCALE);
      qf[dc] = v;
    }
  }

  const f32x4 zero4 = {0.f, 0.f, 0.f, 0.f};
  float m_run = -1e30f, l_run = 0.0f;
  f32x4 oacc[8];
#pragma unroll
  for (int dt = 0; dt < 8; ++dt) oacc[dt] = zero4;

  const int ntiles = 2 * (qt + 1);

  auto stage = [&](int t, int b) {
    const short* gk = Kwp + (size_t)t * 8192 + tid * 8;
    const short* gv = Vwp + (size_t)t * 8192 + tid * 8;
    short* lk = &lds[b][0][tid * 8];
    short* lv = &lds[b][1][tid * 8];
    gload_lds16(gk, lk);            gload_lds16(gk + 4096, lk + 4096);
    gload_lds16(gv, lv);            gload_lds16(gv + 4096, lv + 4096);
  };

  stage(0, 0);                                // prologue: 4 loads in flight

  for (int t = 0; t < ntiles; ++t) {
    const int cur = t & 1;
    __builtin_amdgcn_s_barrier();             // everyone done reading buf we overwrite
    if (t + 1 < ntiles) {
      stage(t + 1, cur ^ 1);
      asm volatile("s_waitcnt vmcnt(4)" ::: "memory");   // tile t's loads landed
    } else {
      asm volatile("s_waitcnt vmcnt(0)" ::: "memory");
    }
    __builtin_amdgcn_s_barrier();             // all waves' tile-t loads landed
    __builtin_amdgcn_sched_barrier(0);

    const int kv0 = t * KVBLK;
    if (q0w + 15 < kv0) continue;             // wave fully masked: stage-only

    const short* Kl = &lds[cur][0][0];
    const short* Vl = &lds[cur][1][0];

    // ---- S^T = K * Q^T : lane holds S[q0w+lr][kv0 + mt*16 + lg*4 + r] ----
    f32x4 st[4];
#pragma unroll
    for (int mt = 0; mt < 4; ++mt) st[mt] = zero4;
    __builtin_amdgcn_s_setprio(1);
#pragma unroll
    for (int dc = 0; dc < 4; ++dc) {
#pragma unroll
      for (int mt = 0; mt < 4; ++mt) {
        int rowb = (mt * 16 + lr) * 256;
        FragU a;
        a.h[0] = *(const short4*)((const char*)Kl + rowb + ((dc * 64      + lg * 8) ^ sw));
        a.h[1] = *(const short4*)((const char*)Kl + rowb + ((dc * 64 + 32 + lg * 8) ^ sw));
        st[mt] = __builtin_amdgcn_mfma_f32_16x16x32_bf16(a.v, qf[dc], st[mt], 0, 0, 0);
      }
    }
    __builtin_amdgcn_s_setprio(0);

    // ---- causal mask (only tiles overlapping the diagonal) ----
    if (t >= 2 * qt) {
      const int qg = q0w + lr;
#pragma unroll
      for (int mt = 0; mt < 4; ++mt)
#pragma unroll
        for (int r = 0; r < 4; ++r)
          if (kv0 + mt * 16 + lg * 4 + r > qg) st[mt][r] = -1e30f;
    }

    // ---- online softmax with defer-max, fused exp2+pack ----
    float mx = st[0][0];
#pragma unroll
    for (int mt = 0; mt < 4; ++mt)
#pragma unroll
      for (int r = 0; r < 4; ++r) mx = fmaxf(mx, st[mt][r]);
    mx = fmaxf(mx, __shfl_xor(mx, 16));
    mx = fmaxf(mx, __shfl_xor(mx, 32));

    if (!__all(mx - m_run <= 8.0f)) {         // rescale path
      float mnew = fmaxf(m_run, mx);
      float corr = exp2f(m_run - mnew);
      m_run = mnew;
      l_run *= corr;
#pragma unroll
      for (int r = 0; r < 4; ++r) {
        float c = __shfl(corr, (lane & 48) + lg * 4 + r);
#pragma unroll
        for (int dt = 0; dt < 8; ++dt) oacc[dt][r] *= c;
      }
    }

    float rs = 0.0f;
    short8 pf[2];
#pragma unroll
    for (int c = 0; c < 2; ++c) {
      short8 v;
#pragma unroll
      for (int j = 0; j < 4; ++j) {
        float e = exp2f(st[2 * c][j] - m_run);     rs += e; v[j]     = f2bf(e);
      }
#pragma unroll
      for (int j = 0; j < 4; ++j) {
        float e = exp2f(st[2 * c + 1][j] - m_run); rs += e; v[4 + j] = f2bf(e);
      }
      pf[c] = v;
    }
    rs += __shfl_xor(rs, 16);
    rs += __shfl_xor(rs, 32);
    l_run += rs;

    // ---- O += P * V ----
    __builtin_amdgcn_s_setprio(1);
#pragma unroll
    for (int dt = 0; dt < 8; ++dt) {
      int rowb = (dt * 16 + lr) * 128;
#pragma unroll
      for (int c = 0; c < 2; ++c) {
        FragU b;
        b.h[0] = *(const short4*)((const char*)Vl + rowb + ((c * 64      + lg * 8) ^ sw));
        b.h[1] = *(const short4*)((const char*)Vl + rowb + ((c * 64 + 32 + lg * 8) ^ sw));
        oacc[dt] = __builtin_amdgcn_mfma_f32_16x16x32_bf16(pf[c], b.v, oacc[dt], 0, 0, 0);
      }
    }
    __builtin_amdgcn_s_setprio(0);
  }

  // ---- epilogue ----
#pragma unroll
  for (int r = 0; r < 4; ++r) {
    float li = __shfl(l_run, (lane & 48) + lg * 4 + r);
    float inv = 1.0f / li;
    float* orow = Op + (size_t)(q0w + lg * 4 + r) * Dc;
#pragma unroll
    for (int dt = 0; dt < 8; ++dt)
      orow[dt * 16 + lr] = oacc[dt][r] * inv;
  }
}

// ===================== R1 fallback (ws too small) =====================
__device__ inline unsigned packbf(float a, float b) {
  return (unsigned)(unsigned short)f2bf(a) | ((unsigned)(unsigned short)f2bf(b) << 16);
}

__global__ __launch_bounds__(256, 2) void attn_fb(
    const float* __restrict__ Qg, const float* __restrict__ Kg,
    const float* __restrict__ Vg, float* __restrict__ Og) {
  __shared__ __align__(16) short Klds[KVBLK * Dc];
  __shared__ __align__(16) short Vt[Dc * 68];
  const int tid = threadIdx.x, wave = tid >> 6, lane = tid & 63;
  const int lg = lane >> 4, lr = lane & 15;
  const int bid = blockIdx.x;
  const int bh = bid & (BH - 1);
  const int qt = 31 - (bid >> 5);
  const int q0w = qt * 64 + wave * 16;
  const float* Qp = Qg + (size_t)bh * Lc * Dc;
  const float* Kp = Kg + (size_t)bh * Lc * Dc;
  const float* Vp = Vg + (size_t)bh * Lc * Dc;
  float* Op = Og + (size_t)bh * Lc * Dc;
  short8 qf[4];
  {
    const float* qrow = Qp + (size_t)(q0w + lr) * Dc;
#pragma unroll
    for (int dc = 0; dc < 4; ++dc) {
      float4 a = *(const float4*)(qrow + dc * 32 + lg * 4);
      float4 b = *(const float4*)(qrow + dc * 32 + 16 + lg * 4);
      short8 v;
      v[0]=f2bf(a.x*SCALE); v[1]=f2bf(a.y*SCALE); v[2]=f2bf(a.z*SCALE); v[3]=f2bf(a.w*SCALE);
      v[4]=f2bf(b.x*SCALE); v[5]=f2bf(b.y*SCALE); v[6]=f2bf(b.z*SCALE); v[7]=f2bf(b.w*SCALE);
      qf[dc] = v;
    }
  }
  const f32x4 zero4 = {0.f,0.f,0.f,0.f};
  float m_run = -1e30f, l_run = 0.0f;
  f32x4 oacc[8];
#pragma unroll
  for (int dt = 0; dt < 8; ++dt) oacc[dt] = zero4;
  const int ntiles = qt + 1, c4 = tid & 31, rK = tid >> 5;
  for (int t = 0; t < ntiles; ++t) {
    const int kv0 = t * KVBLK;
    __syncthreads();
#pragma unroll
    for (int p = 0; p < 8; ++p) {
      int row = rK + p * 8;
      float4 k4 = *(const float4*)(Kp + (size_t)(kv0 + row) * Dc + c4 * 4);
      short4 pk; pk.x=f2bf(k4.x); pk.y=f2bf(k4.y); pk.z=f2bf(k4.z); pk.w=f2bf(k4.w);
      *(short4*)((char*)Klds + row * 256 + ((c4 * 8) ^ ((row & 7) << 4))) = pk;
    }
#pragma unroll
    for (int p = 0; p < 4; ++p) {
      int r0 = rK * 2 + p * 16;
      float4 v0 = *(const float4*)(Vp + (size_t)(kv0 + r0) * Dc + c4 * 4);
      float4 v1 = *(const float4*)(Vp + (size_t)(kv0 + r0 + 1) * Dc + c4 * 4);
      char* vb = (char*)Vt + r0 * 2;
      *(unsigned*)(vb + (c4*4+0)*136) = packbf(v0.x, v1.x);
      *(unsigned*)(vb + (c4*4+1)*136) = packbf(v0.y, v1.y);
      *(unsigned*)(vb + (c4*4+2)*136) = packbf(v0.z, v1.z);
      *(unsigned*)(vb + (c4*4+3)*136) = packbf(v0.w, v1.w);
    }
    __syncthreads();
    f32x4 st[4];
#pragma unroll
    for (int mt = 0; mt < 4; ++mt) st[mt] = zero4;
#pragma unroll
    for (int dc = 0; dc < 4; ++dc)
#pragma unroll
      for (int mt = 0; mt < 4; ++mt) {
        int row = mt * 16 + lr, sw2 = (row & 7) << 4;
        FragU a;
        a.h[0] = *(short4*)((char*)Klds + row*256 + ((dc*64      + lg*8) ^ sw2));
        a.h[1] = *(short4*)((char*)Klds + row*256 + ((dc*64 + 32 + lg*8) ^ sw2));
        st[mt] = __builtin_amdgcn_mfma_f32_16x16x32_bf16(a.v, qf[dc], st[mt], 0, 0, 0);
      }
    if (t == ntiles - 1) {
      const int qg = q0w + lr;
#pragma unroll
      for (int mt = 0; mt < 4; ++mt)
#pragma unroll
        for (int r = 0; r < 4; ++r)
          if (kv0 + mt * 16 + lg * 4 + r > qg) st[mt][r] = -1e30f;
    }
    float mx = st[0][0];
#pragma unroll
    for (int mt = 0; mt < 4; ++mt)
#pragma unroll
      for (int r = 0; r < 4; ++r) mx = fmaxf(mx, st[mt][r]);
    mx = fmaxf(mx, __shfl_xor(mx, 16));
    mx = fmaxf(mx, __shfl_xor(mx, 32));
    float mnew = fmaxf(m_run, mx);
    float corr = exp2f(m_run - mnew);
    m_run = mnew;
    float pr[4][4]; float rs = 0.0f;
#pragma unroll
    for (int mt = 0; mt < 4; ++mt)
#pragma unroll
      for (int r = 0; r < 4; ++r) { float e = exp2f(st[mt][r] - mnew); pr[mt][r] = e; rs += e; }
    rs += __shfl_xor(rs, 16);
    rs += __shfl_xor(rs, 32);
    l_run = l_run * corr + rs;
#pragma unroll
    for (int r = 0; r < 4; ++r) {
      float c = __shfl(corr, (lane & 48) + lg * 4 + r);
#pragma unroll
      for (int dt = 0; dt < 8; ++dt) oacc[dt][r] *= c;
    }
    short8 pf[2];
#pragma unroll
    for (int c = 0; c < 2; ++c) {
      short8 v;
      v[0]=f2bf(pr[2*c][0]); v[1]=f2bf(pr[2*c][1]); v[2]=f2bf(pr[2*c][2]); v[3]=f2bf(pr[2*c][3]);
      v[4]=f2bf(pr[2*c+1][0]); v[5]=f2bf(pr[2*c+1][1]); v[6]=f2bf(pr[2*c+1][2]); v[7]=f2bf(pr[2*c+1][3]);
      pf[c] = v;
    }
#pragma unroll
    for (int dt = 0; dt < 8; ++dt) {
      int rowb = (dt * 16 + lr) * 136;
#pragma unroll
      for (int c = 0; c < 2; ++c) {
        FragU b;
        b.h[0] = *(short4*)((char*)Vt + rowb + c*64      + lg*8);
        b.h[1] = *(short4*)((char*)Vt + rowb + c*64 + 32 + lg*8);
        oacc[dt] = __builtin_amdgcn_mfma_f32_16x16x32_bf16(pf[c], b.v, oacc[dt], 0, 0, 0);
      }
    }
  }
#pragma unroll
  for (int r = 0; r < 4; ++r) {
    float li = __shfl(l_run, (lane & 48) + lg * 4 + r);
    float inv = 1.0f / li;
    float* orow = Op + (size_t)(q0w + lg * 4 + r) * Dc;
#pragma unroll
    for (int dt = 0; dt < 8; ++dt) orow[dt * 16 + lr] = oacc[dt][r] * inv;
  }
}

} // namespace

extern "C" void kernel_launch(void* const* d_in, const int* in_sizes, int n_in,
                              void* d_out, int out_size, void* d_ws, size_t ws_size,
                              hipStream_t stream) {
  const float* Q = (const float*)d_in[0];
  const float* K = (const float*)d_in[1];
  const float* V = (const float*)d_in[2];
  float* O = (float*)d_out;
  const size_t elems = (size_t)BH * Lc * Dc;          // 8.39M per tensor
  const size_t need  = 2 * elems * sizeof(short);     // 33.5 MB
  if (ws_size >= need) {
    short* Kw = (short*)d_ws;
    short* Vw = Kw + elems;
    conv_k<<<dim3(4096), dim3(256), 0, stream>>>(K, Kw);
    conv_v<<<dim3(1024), dim3(256), 0, stream>>>(V, Vw);
    attn_fwd3<<<dim3(BH * NQT3), dim3(512), 0, stream>>>(Q, Kw, Vw, O);
  } else {
    attn_fb<<<dim3(BH * NKT), dim3(256), 0, stream>>>(Q, K, V, O);
  }
}

// Round 4
// 91.390 us; speedup vs baseline: 1.2609x; 1.2609x over previous
//
#include <hip/hip_runtime.h>
#include <hip/hip_bf16.h>

namespace {

constexpr int Bc = 2, Hc = 16, Lc = 2048, Dc = 128;
constexpr int KVBLK = 64;
constexpr int BH  = Bc * Hc;      // 32
constexpr int NKT = Lc / KVBLK;   // 32
constexpr int QB4 = 128;          // q rows per block
constexpr int NQT4 = Lc / QB4;    // 16
// 1/sqrt(128) * log2(e)  (softmax in exp2 domain)
constexpr float SCALE = 0.08838834764831845f * 1.4426950408889634f;

using f32x4   = __attribute__((ext_vector_type(4))) float;
using f32x16  = __attribute__((ext_vector_type(16))) float;
using short8  = __attribute__((ext_vector_type(8))) short;

union FragU { short8 v; short4 h[2]; };

__device__ inline short f2bf(float f) {
  unsigned u = __builtin_bit_cast(unsigned, f);
  u += 0x7fffu + ((u >> 16) & 1u);          // RNE
  return (short)(u >> 16);
}

__device__ inline void gload_lds16(const short* g, short* l) {
  __builtin_amdgcn_global_load_lds(
      (const __attribute__((address_space(1))) void*)g,
      (__attribute__((address_space(3))) void*)l, 16, 0, 0);
}

// ============ pre-pass: K fp32 -> bf16, k-permuted + XOR-swizzled tiles ============
// Tile = 64 rows x 256B. Logical 16B granule g of row holds k-elements
// {chunk*16 + hi*4 + 0..3, chunk*16 + 8 + hi*4 + 0..3} where chunk=g>>1, hi=g&1
// (matches mfma_32x32x16 A/B fragment = one b128). Physical granule x stores
// logical granule x ^ (row&7)  (bank swizzle).
__global__ __launch_bounds__(256) void conv_k(const float* __restrict__ Kg,
                                              short* __restrict__ Kw) {
  int tid = blockIdx.x * 256 + threadIdx.x;   // 1,048,576 total
  int x   = tid & 15;                         // physical 16B granule
  int row = (tid >> 4) & 63;
  int tb  = tid >> 10;                        // bh*32 + t
  int g   = x ^ (row & 7);                    // logical granule
  int chunk = g >> 1, hi = g & 1;
  const float* src = Kg + ((size_t)tb * 64 + row) * 128 + chunk * 16 + hi * 4;
  float4 a = *(const float4*)src;
  float4 b = *(const float4*)(src + 8);
  short8 v;
  v[0] = f2bf(a.x); v[1] = f2bf(a.y); v[2] = f2bf(a.z); v[3] = f2bf(a.w);
  v[4] = f2bf(b.x); v[5] = f2bf(b.y); v[6] = f2bf(b.z); v[7] = f2bf(b.w);
  *(short8*)(Kw + (size_t)tb * 8192 + row * 128 + x * 8) = v;
}

// ============ pre-pass: V fp32 -> bf16 transposed, kv-permuted + swizzled ============
// Vw row = d (128 rows x 128B). Logical granule g holds kv
// {chunk*16 + hi*4 + 0..3, chunk*16 + 8 + hi*4 + 0..3}; physical x = g ^ (d&7).
__global__ __launch_bounds__(256) void conv_v(const float* __restrict__ Vg,
                                              short* __restrict__ Vw) {
  __shared__ short Vs[64 * 130];
  int tb  = blockIdx.x;                       // bh*32 + t
  int tid = threadIdx.x;
  const float* vt = Vg + (size_t)tb * 8192;
#pragma unroll
  for (int p = 0; p < 8; ++p) {
    int g  = p * 256 + tid;                   // float4 index 0..2047
    int kv = g >> 5;
    int c4 = g & 31;
    float4 v = *((const float4*)vt + g);
    short* d = &Vs[kv * 130 + c4 * 4];
    d[0] = f2bf(v.x); d[1] = f2bf(v.y); d[2] = f2bf(v.z); d[3] = f2bf(v.w);
  }
  __syncthreads();
#pragma unroll
  for (int p = 0; p < 4; ++p) {
    int gg = p * 256 + tid;                   // dest granule 0..1023
    int d  = gg >> 3;
    int x  = gg & 7;
    int g  = x ^ (d & 7);                     // logical granule
    int chunk = g >> 1, hi = g & 1;
    int k0 = chunk * 16 + hi * 4;
    short8 o;
#pragma unroll
    for (int j = 0; j < 4; ++j) o[j]     = Vs[(k0 + j)     * 130 + d];
#pragma unroll
    for (int j = 0; j < 4; ++j) o[4 + j] = Vs[(k0 + 8 + j) * 130 + d];
    *(short8*)(Vw + (size_t)tb * 8192 + d * 64 + x * 8) = o;
  }
}

// ===================== main attention (32x32x16 MFMA, 4 waves x 32 q-rows) =====================
__global__ __launch_bounds__(256, 2) void attn_fwd4(
    const float* __restrict__ Qg, const short* __restrict__ Kw,
    const short* __restrict__ Vw, float* __restrict__ Og) {

  // [buf][K=0 / V=1][8192 shorts] = 64 KB -> 2 blocks/CU
  __shared__ __align__(16) short lds[2][2][8192];

  const int tid  = threadIdx.x;
  const int wave = tid >> 6;
  const int lane = tid & 63;
  const int hi   = lane >> 5;                 // k-half select
  const int ln   = lane & 31;
  const int sw   = (ln & 7) << 4;             // XOR swizzle ((row&7)<<4, row&7 == ln&7)

  const int bid = blockIdx.x;
  const int bh  = bid & (BH - 1);             // bid%8 == bh%8 -> head-per-XCD L2 locality
  const int r5  = bid >> 5;                   // 0..15
  // anti-correlated qt: CU's two resident blocks (bid, bid+256) sum to 15
  const int qt  = (bid < 256) ? (NQT4 - 1 - r5) : (r5 - 8);
  const int q0w = qt * QB4 + wave * 32;

  const float* Qp  = Qg + (size_t)bh * Lc * Dc;
  float*       Op  = Og + (size_t)bh * Lc * Dc;
  const short* Kwp = Kw + (size_t)bh * NKT * 8192;
  const short* Vwp = Vw + (size_t)bh * NKT * 8192;

  // ---- preload Q fragments (B-operand: col=q=ln, k = {4hi+e, 8+4hi+e} per 16-chunk) ----
  short8 qf[8];
  {
    const float* qrow = Qp + (size_t)(q0w + ln) * Dc + hi * 4;
#pragma unroll
    for (int ks = 0; ks < 8; ++ks) {
      float4 a = *(const float4*)(qrow + ks * 16);
      float4 b = *(const float4*)(qrow + ks * 16 + 8);
      short8 v;
      v[0] = f2bf(a.x * SCALE); v[1] = f2bf(a.y * SCALE);
      v[2] = f2bf(a.z * SCALE); v[3] = f2bf(a.w * SCALE);
      v[4] = f2bf(b.x * SCALE); v[5] = f2bf(b.y * SCALE);
      v[6] = f2bf(b.z * SCALE); v[7] = f2bf(b.w * SCALE);
      qf[ks] = v;
    }
  }

  float m_run = -1e30f, l_run = 0.0f;
  f32x16 oacc[4];
#pragma unroll
  for (int nt = 0; nt < 4; ++nt)
#pragma unroll
    for (int r = 0; r < 16; ++r) oacc[nt][r] = 0.0f;

  const int ntiles = 2 * (qt + 1);

  auto stage = [&](int t, int b) {
    const short* gk = Kwp + (size_t)t * 8192 + tid * 8;
    const short* gv = Vwp + (size_t)t * 8192 + tid * 8;
    short* lk = &lds[b][0][tid * 8];
    short* lv = &lds[b][1][tid * 8];
#pragma unroll
    for (int i = 0; i < 4; ++i) gload_lds16(gk + i * 2048, lk + i * 2048);
#pragma unroll
    for (int i = 0; i < 4; ++i) gload_lds16(gv + i * 2048, lv + i * 2048);
  };

  stage(0, 0);

  for (int t = 0; t < ntiles; ++t) {
    const int cur = t & 1;
    __builtin_amdgcn_s_barrier();             // all reads of buf we overwrite done
    if (t + 1 < ntiles) {
      stage(t + 1, cur ^ 1);
      asm volatile("s_waitcnt vmcnt(8)" ::: "memory");   // tile t's 8 loads landed
    } else {
      asm volatile("s_waitcnt vmcnt(0)" ::: "memory");
    }
    __builtin_amdgcn_s_barrier();             // all waves' tile-t loads landed
    __builtin_amdgcn_sched_barrier(0);

    const int kv0 = t * KVBLK;
    if (q0w + 31 < kv0) continue;             // wave fully masked: stage-only

    const char* Kl = (const char*)&lds[cur][0][0];
    const char* Vl = (const char*)&lds[cur][1][0];

    // ---- S^T = K * Q^T : D col = q = ln, row kv = kvs*32 + (r&3)+8*(r>>2)+4*hi ----
    f32x16 s0, s1;
#pragma unroll
    for (int r = 0; r < 16; ++r) { s0[r] = 0.0f; s1[r] = 0.0f; }
    __builtin_amdgcn_s_setprio(1);
#pragma unroll
    for (int ks = 0; ks < 8; ++ks) {
      FragU a0, a1;
      int col = (ks * 32 + hi * 16) ^ sw;
      a0.v = *(const short8*)(Kl + ln * 256        + col);
      a1.v = *(const short8*)(Kl + (32 + ln) * 256 + col);
      s0 = __builtin_amdgcn_mfma_f32_32x32x16_bf16(a0.v, qf[ks], s0, 0, 0, 0);
      s1 = __builtin_amdgcn_mfma_f32_32x32x16_bf16(a1.v, qf[ks], s1, 0, 0, 0);
    }
    __builtin_amdgcn_s_setprio(0);

    // ---- causal mask (tiles overlapping the wave's diagonal) ----
    if (kv0 + 63 > q0w) {
      const int qg = q0w + ln;
#pragma unroll
      for (int r = 0; r < 16; ++r) {
        int kvr = kv0 + (r & 3) + 8 * (r >> 2) + 4 * hi;
        if (kvr > qg)      s0[r] = -1e30f;
        if (kvr + 32 > qg) s1[r] = -1e30f;
      }
    }

    // ---- online softmax with defer-max (per lane: one q row, 32 kv values) ----
    float mx = s0[0];
#pragma unroll
    for (int r = 1; r < 16; ++r) mx = fmaxf(mx, s0[r]);
#pragma unroll
    for (int r = 0; r < 16; ++r) mx = fmaxf(mx, s1[r]);
    mx = fmaxf(mx, __shfl_xor(mx, 32));

    if (!__all(mx - m_run <= 8.0f)) {         // rescale path (rare)
      float mnew = fmaxf(m_run, mx);
      float corr = exp2f(m_run - mnew);
      m_run = mnew;
      l_run *= corr;
#pragma unroll
      for (int r = 0; r < 16; ++r) {
        int qrow = (r & 3) + 8 * (r >> 2) + 4 * hi;
        float c = __shfl(corr, qrow);
#pragma unroll
        for (int nt = 0; nt < 4; ++nt) oacc[nt][r] *= c;
      }
    }

    // ---- P = exp2(S - m); pack directly into PV A-fragments (layout-aligned) ----
    float rs = 0.0f;
    short8 pf[4];
#pragma unroll
    for (int kc = 0; kc < 4; ++kc) {
      short8 v;
#pragma unroll
      for (int e = 0; e < 8; ++e) {
        float sv = (kc < 2) ? s0[kc * 8 + e] : s1[(kc - 2) * 8 + e];
        float p = exp2f(sv - m_run);
        rs += p;
        v[e] = f2bf(p);
      }
      pf[kc] = v;
    }
    rs += __shfl_xor(rs, 32);
    l_run += rs;

    // ---- O += P * V ----
    __builtin_amdgcn_s_setprio(1);
#pragma unroll
    for (int nt = 0; nt < 4; ++nt) {
      const char* vrow = Vl + (nt * 32 + ln) * 128;
#pragma unroll
      for (int kc = 0; kc < 4; ++kc) {
        FragU b;
        b.v = *(const short8*)(vrow + ((kc * 32 + hi * 16) ^ sw));
        oacc[nt] = __builtin_amdgcn_mfma_f32_32x32x16_bf16(pf[kc], b.v, oacc[nt], 0, 0, 0);
      }
    }
    __builtin_amdgcn_s_setprio(0);
  }

  // ---- epilogue: O row q = (r&3)+8*(r>>2)+4*hi, col d = nt*32 + ln ----
  float linv = 1.0f / l_run;
#pragma unroll
  for (int r = 0; r < 16; ++r) {
    int qrow = (r & 3) + 8 * (r >> 2) + 4 * hi;
    float il = __shfl(linv, qrow);
    float* orow = Op + (size_t)(q0w + qrow) * Dc + ln;
#pragma unroll
    for (int nt = 0; nt < 4; ++nt)
      orow[nt * 32] = oacc[nt][r] * il;
  }
}

// ===================== R1 fallback (ws too small) =====================
__device__ inline unsigned packbf(float a, float b) {
  return (unsigned)(unsigned short)f2bf(a) | ((unsigned)(unsigned short)f2bf(b) << 16);
}

__global__ __launch_bounds__(256, 2) void attn_fb(
    const float* __restrict__ Qg, const float* __restrict__ Kg,
    const float* __restrict__ Vg, float* __restrict__ Og) {
  __shared__ __align__(16) short Klds[KVBLK * Dc];
  __shared__ __align__(16) short Vt[Dc * 68];
  const int tid = threadIdx.x, wave = tid >> 6, lane = tid & 63;
  const int lg = lane >> 4, lr = lane & 15;
  const int bid = blockIdx.x;
  const int bh = bid & (BH - 1);
  const int qt = 31 - (bid >> 5);
  const int q0w = qt * 64 + wave * 16;
  const float* Qp = Qg + (size_t)bh * Lc * Dc;
  const float* Kp = Kg + (size_t)bh * Lc * Dc;
  const float* Vp = Vg + (size_t)bh * Lc * Dc;
  float* Op = Og + (size_t)bh * Lc * Dc;
  short8 qf[4];
  {
    const float* qrow = Qp + (size_t)(q0w + lr) * Dc;
#pragma unroll
    for (int dc = 0; dc < 4; ++dc) {
      float4 a = *(const float4*)(qrow + dc * 32 + lg * 4);
      float4 b = *(const float4*)(qrow + dc * 32 + 16 + lg * 4);
      short8 v;
      v[0]=f2bf(a.x*SCALE); v[1]=f2bf(a.y*SCALE); v[2]=f2bf(a.z*SCALE); v[3]=f2bf(a.w*SCALE);
      v[4]=f2bf(b.x*SCALE); v[5]=f2bf(b.y*SCALE); v[6]=f2bf(b.z*SCALE); v[7]=f2bf(b.w*SCALE);
      qf[dc] = v;
    }
  }
  const f32x4 zero4 = {0.f,0.f,0.f,0.f};
  float m_run = -1e30f, l_run = 0.0f;
  f32x4 oacc[8];
#pragma unroll
  for (int dt = 0; dt < 8; ++dt) oacc[dt] = zero4;
  const int ntiles = qt + 1, c4 = tid & 31, rK = tid >> 5;
  for (int t = 0; t < ntiles; ++t) {
    const int kv0 = t * KVBLK;
    __syncthreads();
#pragma unroll
    for (int p = 0; p < 8; ++p) {
      int row = rK + p * 8;
      float4 k4 = *(const float4*)(Kp + (size_t)(kv0 + row) * Dc + c4 * 4);
      short4 pk; pk.x=f2bf(k4.x); pk.y=f2bf(k4.y); pk.z=f2bf(k4.z); pk.w=f2bf(k4.w);
      *(short4*)((char*)Klds + row * 256 + ((c4 * 8) ^ ((row & 7) << 4))) = pk;
    }
#pragma unroll
    for (int p = 0; p < 4; ++p) {
      int r0 = rK * 2 + p * 16;
      float4 v0 = *(const float4*)(Vp + (size_t)(kv0 + r0) * Dc + c4 * 4);
      float4 v1 = *(const float4*)(Vp + (size_t)(kv0 + r0 + 1) * Dc + c4 * 4);
      char* vb = (char*)Vt + r0 * 2;
      *(unsigned*)(vb + (c4*4+0)*136) = packbf(v0.x, v1.x);
      *(unsigned*)(vb + (c4*4+1)*136) = packbf(v0.y, v1.y);
      *(unsigned*)(vb + (c4*4+2)*136) = packbf(v0.z, v1.z);
      *(unsigned*)(vb + (c4*4+3)*136) = packbf(v0.w, v1.w);
    }
    __syncthreads();
    f32x4 st[4];
#pragma unroll
    for (int mt = 0; mt < 4; ++mt) st[mt] = zero4;
#pragma unroll
    for (int dc = 0; dc < 4; ++dc)
#pragma unroll
      for (int mt = 0; mt < 4; ++mt) {
        int row = mt * 16 + lr, sw2 = (row & 7) << 4;
        FragU a;
        a.h[0] = *(short4*)((char*)Klds + row*256 + ((dc*64      + lg*8) ^ sw2));
        a.h[1] = *(short4*)((char*)Klds + row*256 + ((dc*64 + 32 + lg*8) ^ sw2));
        st[mt] = __builtin_amdgcn_mfma_f32_16x16x32_bf16(a.v, qf[dc], st[mt], 0, 0, 0);
      }
    if (t == ntiles - 1) {
      const int qg = q0w + lr;
#pragma unroll
      for (int mt = 0; mt < 4; ++mt)
#pragma unroll
        for (int r = 0; r < 4; ++r)
          if (kv0 + mt * 16 + lg * 4 + r > qg) st[mt][r] = -1e30f;
    }
    float mx = st[0][0];
#pragma unroll
    for (int mt = 0; mt < 4; ++mt)
#pragma unroll
      for (int r = 0; r < 4; ++r) mx = fmaxf(mx, st[mt][r]);
    mx = fmaxf(mx, __shfl_xor(mx, 16));
    mx = fmaxf(mx, __shfl_xor(mx, 32));
    float mnew = fmaxf(m_run, mx);
    float corr = exp2f(m_run - mnew);
    m_run = mnew;
    float pr[4][4]; float rs = 0.0f;
#pragma unroll
    for (int mt = 0; mt < 4; ++mt)
#pragma unroll
      for (int r = 0; r < 4; ++r) { float e = exp2f(st[mt][r] - mnew); pr[mt][r] = e; rs += e; }
    rs += __shfl_xor(rs, 16);
    rs += __shfl_xor(rs, 32);
    l_run = l_run * corr + rs;
#pragma unroll
    for (int r = 0; r < 4; ++r) {
      float c = __shfl(corr, (lane & 48) + lg * 4 + r);
#pragma unroll
      for (int dt = 0; dt < 8; ++dt) oacc[dt][r] *= c;
    }
    short8 pf[2];
#pragma unroll
    for (int c = 0; c < 2; ++c) {
      short8 v;
      v[0]=f2bf(pr[2*c][0]); v[1]=f2bf(pr[2*c][1]); v[2]=f2bf(pr[2*c][2]); v[3]=f2bf(pr[2*c][3]);
      v[4]=f2bf(pr[2*c+1][0]); v[5]=f2bf(pr[2*c+1][1]); v[6]=f2bf(pr[2*c+1][2]); v[7]=f2bf(pr[2*c+1][3]);
      pf[c] = v;
    }
#pragma unroll
    for (int dt = 0; dt < 8; ++dt) {
      int rowb = (dt * 16 + lr) * 136;
#pragma unroll
      for (int c = 0; c < 2; ++c) {
        FragU b;
        b.h[0] = *(short4*)((char*)Vt + rowb + c*64      + lg*8);
        b.h[1] = *(short4*)((char*)Vt + rowb + c*64 + 32 + lg*8);
        oacc[dt] = __builtin_amdgcn_mfma_f32_16x16x32_bf16(pf[c], b.v, oacc[dt], 0, 0, 0);
      }
    }
  }
#pragma unroll
  for (int r = 0; r < 4; ++r) {
    float li = __shfl(l_run, (lane & 48) + lg * 4 + r);
    float inv = 1.0f / li;
    float* orow = Op + (size_t)(q0w + lg * 4 + r) * Dc;
#pragma unroll
    for (int dt = 0; dt < 8; ++dt) orow[dt * 16 + lr] = oacc[dt][r] * inv;
  }
}

} // namespace

extern "C" void kernel_launch(void* const* d_in, const int* in_sizes, int n_in,
                              void* d_out, int out_size, void* d_ws, size_t ws_size,
                              hipStream_t stream) {
  const float* Q = (const float*)d_in[0];
  const float* K = (const float*)d_in[1];
  const float* V = (const float*)d_in[2];
  float* O = (float*)d_out;
  const size_t elems = (size_t)BH * Lc * Dc;          // 8.39M per tensor
  const size_t need  = 2 * elems * sizeof(short);     // 33.5 MB
  if (ws_size >= need) {
    short* Kw = (short*)d_ws;
    short* Vw = Kw + elems;
    conv_k<<<dim3(4096), dim3(256), 0, stream>>>(K, Kw);
    conv_v<<<dim3(1024), dim3(256), 0, stream>>>(V, Vw);
    attn_fwd4<<<dim3(BH * NQT4), dim3(256), 0, stream>>>(Q, Kw, Vw, O);
  } else {
    attn_fb<<<dim3(BH * NKT), dim3(256), 0, stream>>>(Q, K, V, O);
  }
}